// Round 1
// baseline (13161.320 us; speedup 1.0000x reference)
//
#include <hip/hip_runtime.h>
#include <cstddef>

#define NN 50000
#define TT 12
#define FIN 128
#define DD 128
#define HH 4
#define EE 800000
#define ETOT (EE + NN)
#define NEG 0.2f

// ---------------- GAT input GEMM: h = x[:,t,:] @ W_gat  ([N,128]@[128,128]) ----------------
__global__ __launch_bounds__(256) void gat_gemm_kernel(
    const float* __restrict__ x, const float* __restrict__ Wg,
    float* __restrict__ hout, int t)
{
    __shared__ float sA[64][33];
    __shared__ float sB[32][128];
    const int bm = blockIdx.x * 64;
    const int tid = threadIdx.x;
    const int tc = tid & 15;   // col group: cols = tc + 16*m
    const int tr = tid >> 4;   // node group: nodes tr*4 .. tr*4+3
    float acc[4][8];
    #pragma unroll
    for (int i = 0; i < 4; i++)
        #pragma unroll
        for (int m = 0; m < 8; m++) acc[i][m] = 0.f;

    for (int k0 = 0; k0 < FIN; k0 += 32) {
        #pragma unroll
        for (int i = 0; i < 2; i++) {
            int fl = tid * 2 + i;          // 0..511
            int row = fl >> 3, q = fl & 7;
            int n = bm + row;
            float4 v = make_float4(0.f, 0.f, 0.f, 0.f);
            if (n < NN) v = *(const float4*)&x[((size_t)n * TT + t) * FIN + k0 + q * 4];
            sA[row][q * 4 + 0] = v.x; sA[row][q * 4 + 1] = v.y;
            sA[row][q * 4 + 2] = v.z; sA[row][q * 4 + 3] = v.w;
        }
        #pragma unroll
        for (int i = 0; i < 4; i++) {
            int fl = tid * 4 + i;          // 0..1023
            int row = fl >> 5, q = fl & 31;
            *(float4*)&sB[row][q * 4] = *(const float4*)&Wg[(size_t)(k0 + row) * DD + q * 4];
        }
        __syncthreads();
        #pragma unroll
        for (int kk = 0; kk < 32; kk++) {
            float b[8];
            #pragma unroll
            for (int m = 0; m < 8; m++) b[m] = sB[kk][tc + 16 * m];
            #pragma unroll
            for (int i = 0; i < 4; i++) {
                float a = sA[tr * 4 + i][kk];
                #pragma unroll
                for (int m = 0; m < 8; m++) acc[i][m] += a * b[m];
            }
        }
        __syncthreads();
    }
    #pragma unroll
    for (int i = 0; i < 4; i++) {
        int n = bm + tr * 4 + i;
        if (n < NN) {
            #pragma unroll
            for (int m = 0; m < 8; m++) hout[(size_t)n * DD + tc + 16 * m] = acc[i][m];
        }
    }
}

// ---------------- per-node attention logits ----------------
__global__ __launch_bounds__(256) void al_kernel(
    const float* __restrict__ h, const float* __restrict__ a_src,
    const float* __restrict__ a_dst, float* __restrict__ alsrc, float* __restrict__ aldst)
{
    int gid = blockIdx.x * 256 + threadIdx.x;
    if (gid >= NN * HH) return;
    int n = gid >> 2, hd = gid & 3;
    const float* hp = &h[(size_t)n * DD + hd * 32];
    const float* ap = &a_src[hd * 32];
    const float* bp = &a_dst[hd * 32];
    float s1 = 0.f, s2 = 0.f;
    #pragma unroll
    for (int i = 0; i < 32; i += 4) {
        float4 hv = *(const float4*)&hp[i];
        float4 av = *(const float4*)&ap[i];
        float4 dv = *(const float4*)&bp[i];
        s1 += hv.x * av.x + hv.y * av.y + hv.z * av.z + hv.w * av.w;
        s2 += hv.x * dv.x + hv.y * dv.y + hv.z * dv.z + hv.w * dv.w;
    }
    alsrc[gid] = s1;
    aldst[gid] = s2;
}

// ---------------- edge pass 1: softmax denominators ----------------
__global__ __launch_bounds__(256) void edge_denom_kernel(
    const int* __restrict__ src, const int* __restrict__ dst,
    const float* __restrict__ alsrc, const float* __restrict__ aldst,
    float* __restrict__ denom)
{
    int gid = blockIdx.x * 256 + threadIdx.x;
    if (gid >= ETOT) return;
    int s, d;
    if (gid < EE) { s = src[gid]; d = dst[gid]; }
    else { s = gid - EE; d = s; }
    float4 as = *(const float4*)&alsrc[(size_t)s * 4];
    float4 ad = *(const float4*)&aldst[(size_t)d * 4];
    float e0 = as.x + ad.x, e1 = as.y + ad.y, e2 = as.z + ad.z, e3 = as.w + ad.w;
    e0 = e0 > 0.f ? e0 : NEG * e0;
    e1 = e1 > 0.f ? e1 : NEG * e1;
    e2 = e2 > 0.f ? e2 : NEG * e2;
    e3 = e3 > 0.f ? e3 : NEG * e3;
    atomicAdd(&denom[(size_t)d * 4 + 0], expf(e0));
    atomicAdd(&denom[(size_t)d * 4 + 1], expf(e1));
    atomicAdd(&denom[(size_t)d * 4 + 2], expf(e2));
    atomicAdd(&denom[(size_t)d * 4 + 3], expf(e3));
}

// ---------------- edge pass 2: weighted message scatter ----------------
__global__ __launch_bounds__(256) void edge_msg_kernel(
    const int* __restrict__ src, const int* __restrict__ dst,
    const float* __restrict__ alsrc, const float* __restrict__ aldst,
    const float* __restrict__ denom, const float* __restrict__ h,
    float* __restrict__ gacc)
{
    int e = blockIdx.x * 2 + (threadIdx.x >> 7);
    if (e >= ETOT) return;
    int c = threadIdx.x & 127;
    int s, d;
    if (e < EE) { s = src[e]; d = dst[e]; }
    else { s = e - EE; d = s; }
    int hd = c >> 5;
    float a = alsrc[(size_t)s * 4 + hd] + aldst[(size_t)d * 4 + hd];
    a = a > 0.f ? a : NEG * a;
    float alpha = expf(a) / (denom[(size_t)d * 4 + hd] + 1e-16f);
    atomicAdd(&gacc[(size_t)d * DD + c], h[(size_t)s * DD + c] * alpha);
}

// ---------------- bias + relu (in place) ----------------
__global__ __launch_bounds__(256) void relu_bias_kernel(
    float* __restrict__ g, const float* __restrict__ b)
{
    int gid = blockIdx.x * 256 + threadIdx.x;
    if (gid >= NN * DD / 4) return;
    float4 v = *(float4*)&g[(size_t)gid * 4];
    const float* bp = &b[(gid * 4) & (DD - 1)];
    v.x = fmaxf(v.x + bp[0], 0.f);
    v.y = fmaxf(v.y + bp[1], 0.f);
    v.z = fmaxf(v.z + bp[2], 0.f);
    v.w = fmaxf(v.w + bp[3], 0.f);
    *(float4*)&g[(size_t)gid * 4] = v;
}

// ---------------- fused GRU step: hstate = GRU(g, hstate) ----------------
// Block handles 32 nodes. Concat-K GEMM over K=256 (g | h), BK=16, all 384 gate
// rows; n-gate keeps the g- and h- halves in separate accumulators.
__global__ __launch_bounds__(256) void gru_kernel(
    const float* __restrict__ g, float* __restrict__ hstate,
    const float* __restrict__ Wih, const float* __restrict__ Whh,
    const float* __restrict__ bih, const float* __restrict__ bhh)
{
    __shared__ float sA[32][260];   // [node][k] k<128: g, k>=128: h
    __shared__ float sB[16][388];   // [kk][j]  j in 0..383
    const int n0 = blockIdx.x * 32;
    const int tid = threadIdx.x;
    const int tc = tid & 15;        // jj = tc*8 + u (u 0..7)
    const int tr = tid >> 4;        // nodes tr*2, tr*2+1

    // stage A (whole K range)
    #pragma unroll
    for (int i = 0; i < 8; i++) {
        int fl = tid + 256 * i;     // 0..2047
        int row = fl >> 6;
        int q = fl & 63;
        int n = n0 + row;
        float4 v = make_float4(0.f, 0.f, 0.f, 0.f);
        if (n < NN) {
            if (q < 32) v = *(const float4*)&g[(size_t)n * DD + q * 4];
            else        v = *(const float4*)&hstate[(size_t)n * DD + (q - 32) * 4];
        }
        float* dp = &sA[row][q * 4];
        dp[0] = v.x; dp[1] = v.y; dp[2] = v.z; dp[3] = v.w;
    }

    float accr[2][8], accz[2][8], accin[2][8], acchn[2][8];
    #pragma unroll
    for (int i = 0; i < 2; i++)
        #pragma unroll
        for (int u = 0; u < 8; u++) { accr[i][u] = 0.f; accz[i][u] = 0.f; accin[i][u] = 0.f; acchn[i][u] = 0.f; }

    for (int k0 = 0; k0 < 256; k0 += 16) {
        __syncthreads();
        const float* W = (k0 < 128) ? Wih : Whh;
        const int kbase = (k0 < 128) ? k0 : (k0 - 128);
        #pragma unroll
        for (int i = 0; i < 6; i++) {
            int fl = tid + 256 * i;      // 0..1535
            int j = fl >> 2;
            int qk = fl & 3;
            float4 w = *(const float4*)&W[(size_t)j * DD + kbase + qk * 4];
            sB[qk * 4 + 0][j] = w.x;
            sB[qk * 4 + 1][j] = w.y;
            sB[qk * 4 + 2][j] = w.z;
            sB[qk * 4 + 3][j] = w.w;
        }
        __syncthreads();
        const bool part2 = (k0 >= 128);
        #pragma unroll
        for (int kk = 0; kk < 16; kk++) {
            float a0 = sA[tr * 2 + 0][k0 + kk];
            float a1 = sA[tr * 2 + 1][k0 + kk];
            float4 br0 = *(const float4*)&sB[kk][tc * 8];
            float4 br1 = *(const float4*)&sB[kk][tc * 8 + 4];
            float4 bz0 = *(const float4*)&sB[kk][128 + tc * 8];
            float4 bz1 = *(const float4*)&sB[kk][128 + tc * 8 + 4];
            float4 bn0 = *(const float4*)&sB[kk][256 + tc * 8];
            float4 bn1 = *(const float4*)&sB[kk][256 + tc * 8 + 4];
            const float br[8] = {br0.x, br0.y, br0.z, br0.w, br1.x, br1.y, br1.z, br1.w};
            const float bz[8] = {bz0.x, bz0.y, bz0.z, bz0.w, bz1.x, bz1.y, bz1.z, bz1.w};
            const float bn[8] = {bn0.x, bn0.y, bn0.z, bn0.w, bn1.x, bn1.y, bn1.z, bn1.w};
            #pragma unroll
            for (int u = 0; u < 8; u++) {
                accr[0][u] += a0 * br[u]; accr[1][u] += a1 * br[u];
                accz[0][u] += a0 * bz[u]; accz[1][u] += a1 * bz[u];
            }
            if (!part2) {
                #pragma unroll
                for (int u = 0; u < 8; u++) { accin[0][u] += a0 * bn[u]; accin[1][u] += a1 * bn[u]; }
            } else {
                #pragma unroll
                for (int u = 0; u < 8; u++) { acchn[0][u] += a0 * bn[u]; acchn[1][u] += a1 * bn[u]; }
            }
        }
    }

    #pragma unroll
    for (int i = 0; i < 2; i++) {
        int n = n0 + tr * 2 + i;
        if (n >= NN) continue;
        #pragma unroll
        for (int u = 0; u < 8; u++) {
            int jj = tc * 8 + u;
            float rp = accr[i][u] + bih[jj] + bhh[jj];
            float zp = accz[i][u] + bih[128 + jj] + bhh[128 + jj];
            float r = 1.f / (1.f + expf(-rp));
            float z = 1.f / (1.f + expf(-zp));
            float nv = tanhf(accin[i][u] + bih[256 + jj] + r * (acchn[i][u] + bhh[256 + jj]));
            float hold = sA[tr * 2 + i][128 + jj];
            hstate[(size_t)n * DD + jj] = (1.f - z) * nv + z * hold;
        }
    }
}

// ---------------- final linear: out[n] = h[n,:] . W_lin + b ----------------
__global__ __launch_bounds__(256) void out_kernel(
    const float* __restrict__ h, const float* __restrict__ wl,
    const float* __restrict__ bl, float* __restrict__ out)
{
    int lane = threadIdx.x & 63;
    int n = blockIdx.x * 4 + (threadIdx.x >> 6);
    if (n >= NN) return;
    const float* hp = &h[(size_t)n * DD];
    float s = hp[lane] * wl[lane] + hp[64 + lane] * wl[64 + lane];
    #pragma unroll
    for (int off = 32; off; off >>= 1) s += __shfl_down(s, off);
    if (lane == 0) out[n] = s + bl[0];
}

extern "C" void kernel_launch(void* const* d_in, const int* in_sizes, int n_in,
                              void* d_out, int out_size, void* d_ws, size_t ws_size,
                              hipStream_t stream)
{
    const float* x     = (const float*)d_in[0];
    const int*   ei    = (const int*)d_in[1];
    const float* Wg    = (const float*)d_in[2];
    const float* a_src = (const float*)d_in[3];
    const float* a_dst = (const float*)d_in[4];
    const float* b_gat = (const float*)d_in[5];
    const float* Wih   = (const float*)d_in[6];
    const float* Whh   = (const float*)d_in[7];
    const float* bih   = (const float*)d_in[8];
    const float* bhh   = (const float*)d_in[9];
    const float* Wl    = (const float*)d_in[10];
    const float* bl    = (const float*)d_in[11];
    float* out = (float*)d_out;

    float* ws = (float*)d_ws;
    float* hbuf   = ws;                         // N*128
    float* gbuf   = hbuf   + (size_t)NN * DD;   // N*128
    float* hstate = gbuf   + (size_t)NN * DD;   // N*128
    float* alsrc  = hstate + (size_t)NN * DD;   // N*4
    float* aldst  = alsrc  + (size_t)NN * HH;   // N*4
    float* denom  = aldst  + (size_t)NN * HH;   // N*4

    hipMemsetAsync(hstate, 0, (size_t)NN * DD * sizeof(float), stream);

    for (int t = 0; t < TT; t++) {
        const int* srcp = ei + (size_t)t * 2 * EE;
        const int* dstp = srcp + EE;

        gat_gemm_kernel<<<(NN + 63) / 64, 256, 0, stream>>>(x, Wg, hbuf, t);
        al_kernel<<<(NN * HH + 255) / 256, 256, 0, stream>>>(hbuf, a_src, a_dst, alsrc, aldst);
        hipMemsetAsync(denom, 0, (size_t)NN * HH * sizeof(float), stream);
        hipMemsetAsync(gbuf, 0, (size_t)NN * DD * sizeof(float), stream);
        edge_denom_kernel<<<(ETOT + 255) / 256, 256, 0, stream>>>(srcp, dstp, alsrc, aldst, denom);
        edge_msg_kernel<<<(ETOT + 1) / 2, 256, 0, stream>>>(srcp, dstp, alsrc, aldst, denom, hbuf, gbuf);
        relu_bias_kernel<<<(NN * DD / 4 + 255) / 256, 256, 0, stream>>>(gbuf, b_gat);
        gru_kernel<<<(NN + 31) / 32, 256, 0, stream>>>(gbuf, hstate, Wih, Whh, bih, bhh);
    }
    out_kernel<<<(NN + 3) / 4, 256, 0, stream>>>(hstate, Wl, bl, out);
}

// Round 2
// 7885.192 us; speedup vs baseline: 1.6691x; 1.6691x over previous
//
#include <hip/hip_runtime.h>
#include <cstddef>

#define NN 50000
#define TT 12
#define FIN 128
#define DD 128
#define HH 4
#define EE 800000
#define ETOT (EE + NN)
#define NEG 0.2f

typedef __attribute__((ext_vector_type(8))) short bf16x8;
typedef __attribute__((ext_vector_type(4))) float f32x4;

__device__ __forceinline__ ushort f2b(float x) {
    unsigned int u = __builtin_bit_cast(unsigned int, x);
    unsigned int r = (u + 0x7FFFu + ((u >> 16) & 1u)) >> 16;
    return (ushort)r;
}

// ---------------- GAT input GEMM: h = x[:,t,:] @ W_gat  ([N,128]@[128,128]) ----------------
__global__ __launch_bounds__(256) void gat_gemm_kernel(
    const float* __restrict__ x, const float* __restrict__ Wg,
    float* __restrict__ hout, int t)
{
    __shared__ float sA[64][33];
    __shared__ float sB[32][128];
    const int bm = blockIdx.x * 64;
    const int tid = threadIdx.x;
    const int tc = tid & 15;   // col group: cols = tc + 16*m
    const int tr = tid >> 4;   // node group: nodes tr*4 .. tr*4+3
    float acc[4][8];
    #pragma unroll
    for (int i = 0; i < 4; i++)
        #pragma unroll
        for (int m = 0; m < 8; m++) acc[i][m] = 0.f;

    for (int k0 = 0; k0 < FIN; k0 += 32) {
        #pragma unroll
        for (int i = 0; i < 2; i++) {
            int fl = tid * 2 + i;          // 0..511
            int row = fl >> 3, q = fl & 7;
            int n = bm + row;
            float4 v = make_float4(0.f, 0.f, 0.f, 0.f);
            if (n < NN) v = *(const float4*)&x[((size_t)n * TT + t) * FIN + k0 + q * 4];
            sA[row][q * 4 + 0] = v.x; sA[row][q * 4 + 1] = v.y;
            sA[row][q * 4 + 2] = v.z; sA[row][q * 4 + 3] = v.w;
        }
        #pragma unroll
        for (int i = 0; i < 4; i++) {
            int fl = tid * 4 + i;          // 0..1023
            int row = fl >> 5, q = fl & 31;
            *(float4*)&sB[row][q * 4] = *(const float4*)&Wg[(size_t)(k0 + row) * DD + q * 4];
        }
        __syncthreads();
        #pragma unroll
        for (int kk = 0; kk < 32; kk++) {
            float b[8];
            #pragma unroll
            for (int m = 0; m < 8; m++) b[m] = sB[kk][tc + 16 * m];
            #pragma unroll
            for (int i = 0; i < 4; i++) {
                float a = sA[tr * 4 + i][kk];
                #pragma unroll
                for (int m = 0; m < 8; m++) acc[i][m] += a * b[m];
            }
        }
        __syncthreads();
    }
    #pragma unroll
    for (int i = 0; i < 4; i++) {
        int n = bm + tr * 4 + i;
        if (n < NN) {
            #pragma unroll
            for (int m = 0; m < 8; m++) hout[(size_t)n * DD + tc + 16 * m] = acc[i][m];
        }
    }
}

// ---------------- per-node attention logits ----------------
__global__ __launch_bounds__(256) void al_kernel(
    const float* __restrict__ h, const float* __restrict__ a_src,
    const float* __restrict__ a_dst, float* __restrict__ alsrc, float* __restrict__ aldst)
{
    int gid = blockIdx.x * 256 + threadIdx.x;
    if (gid >= NN * HH) return;
    int n = gid >> 2, hd = gid & 3;
    const float* hp = &h[(size_t)n * DD + hd * 32];
    const float* ap = &a_src[hd * 32];
    const float* bp = &a_dst[hd * 32];
    float s1 = 0.f, s2 = 0.f;
    #pragma unroll
    for (int i = 0; i < 32; i += 4) {
        float4 hv = *(const float4*)&hp[i];
        float4 av = *(const float4*)&ap[i];
        float4 dv = *(const float4*)&bp[i];
        s1 += hv.x * av.x + hv.y * av.y + hv.z * av.z + hv.w * av.w;
        s2 += hv.x * dv.x + hv.y * dv.y + hv.z * dv.z + hv.w * dv.w;
    }
    alsrc[gid] = s1;
    aldst[gid] = s2;
}

// ---------------- edge pass 1: softmax denominators ----------------
__global__ __launch_bounds__(256) void edge_denom_kernel(
    const int* __restrict__ src, const int* __restrict__ dst,
    const float* __restrict__ alsrc, const float* __restrict__ aldst,
    float* __restrict__ denom)
{
    int gid = blockIdx.x * 256 + threadIdx.x;
    if (gid >= ETOT) return;
    int s, d;
    if (gid < EE) { s = src[gid]; d = dst[gid]; }
    else { s = gid - EE; d = s; }
    float4 as = *(const float4*)&alsrc[(size_t)s * 4];
    float4 ad = *(const float4*)&aldst[(size_t)d * 4];
    float e0 = as.x + ad.x, e1 = as.y + ad.y, e2 = as.z + ad.z, e3 = as.w + ad.w;
    e0 = e0 > 0.f ? e0 : NEG * e0;
    e1 = e1 > 0.f ? e1 : NEG * e1;
    e2 = e2 > 0.f ? e2 : NEG * e2;
    e3 = e3 > 0.f ? e3 : NEG * e3;
    atomicAdd(&denom[(size_t)d * 4 + 0], expf(e0));
    atomicAdd(&denom[(size_t)d * 4 + 1], expf(e1));
    atomicAdd(&denom[(size_t)d * 4 + 2], expf(e2));
    atomicAdd(&denom[(size_t)d * 4 + 3], expf(e3));
}

// ---------------- edge pass 2: weighted message scatter ----------------
__global__ __launch_bounds__(256) void edge_msg_kernel(
    const int* __restrict__ src, const int* __restrict__ dst,
    const float* __restrict__ alsrc, const float* __restrict__ aldst,
    const float* __restrict__ denom, const float* __restrict__ h,
    float* __restrict__ gacc)
{
    int e = blockIdx.x * 2 + (threadIdx.x >> 7);
    if (e >= ETOT) return;
    int c = threadIdx.x & 127;
    int s, d;
    if (e < EE) { s = src[e]; d = dst[e]; }
    else { s = e - EE; d = s; }
    int hd = c >> 5;
    float a = alsrc[(size_t)s * 4 + hd] + aldst[(size_t)d * 4 + hd];
    a = a > 0.f ? a : NEG * a;
    float alpha = expf(a) / (denom[(size_t)d * 4 + hd] + 1e-16f);
    atomicAdd(&gacc[(size_t)d * DD + c], h[(size_t)s * DD + c] * alpha);
}

// ---------------- bias + relu -> bf16 A-buffer (g half) ----------------
__global__ __launch_bounds__(256) void relu_bias_bf16_kernel(
    const float* __restrict__ g, const float* __restrict__ b, ushort* __restrict__ Abuf)
{
    int gid = blockIdx.x * 256 + threadIdx.x;      // node*16 + chunk
    if (gid >= NN * 16) return;
    int n = gid >> 4, c0 = (gid & 15) * 8;
    float4 v0 = *(const float4*)&g[(size_t)n * DD + c0];
    float4 v1 = *(const float4*)&g[(size_t)n * DD + c0 + 4];
    float4 b0 = *(const float4*)&b[c0];
    float4 b1 = *(const float4*)&b[c0 + 4];
    ushort o[8];
    o[0] = f2b(fmaxf(v0.x + b0.x, 0.f));
    o[1] = f2b(fmaxf(v0.y + b0.y, 0.f));
    o[2] = f2b(fmaxf(v0.z + b0.z, 0.f));
    o[3] = f2b(fmaxf(v0.w + b0.w, 0.f));
    o[4] = f2b(fmaxf(v1.x + b1.x, 0.f));
    o[5] = f2b(fmaxf(v1.y + b1.y, 0.f));
    o[6] = f2b(fmaxf(v1.z + b1.z, 0.f));
    o[7] = f2b(fmaxf(v1.w + b1.w, 0.f));
    *(uint4*)&Abuf[(size_t)n * 256 + c0] = *(uint4*)o;
}

// ---------------- prep: build pre-swizzled bf16 gate matrix ----------------
// Logical B[k 0..255][col 0..511]: col blocks of 128 = {r, z, i_n, h_n}.
//   r,z:  k<128 -> Wih[col%384-block row][k], k>=128 -> Whh[...][k-128]
//   i_n:  Wih n-rows for k<128, zero for k>=128; h_n: zero / Whh n-rows.
// Stored in MFMA fragment order: frag fi = kb*32 + c, then [lane][j] 8 bf16.
__global__ __launch_bounds__(256) void prep_b_kernel(
    const float* __restrict__ Wih, const float* __restrict__ Whh, ushort* __restrict__ Bswz)
{
    int idx = blockIdx.x * 256 + threadIdx.x;      // < 131072
    int fi = idx >> 9;
    int rem = idx & 511;
    int l = rem >> 3, j = rem & 7;
    int kb = fi >> 5, c = fi & 31;
    int g = c >> 3, cf = c & 7;
    int k = kb * 32 + (l >> 4) * 8 + j;
    int jj = cf * 16 + (l & 15);
    float v;
    if (g == 0)      v = (k < 128) ? Wih[(size_t)jj * DD + k]         : Whh[(size_t)jj * DD + k - 128];
    else if (g == 1) v = (k < 128) ? Wih[(size_t)(128 + jj) * DD + k] : Whh[(size_t)(128 + jj) * DD + k - 128];
    else if (g == 2) v = (k < 128) ? Wih[(size_t)(256 + jj) * DD + k] : 0.f;
    else             v = (k < 128) ? 0.f : Whh[(size_t)(256 + jj) * DD + k - 128];
    Bswz[idx] = f2b(v);
}

// ---------------- fused GRU step via bf16 MFMA ----------------
// C[64 nodes][512] = A[64][256] @ B[256][512]; cols: [r | z | i_n | h_n].
// Wave w owns all 64 rows x cols {(g*8 + 2w + s)*16 ..} so the epilogue is
// register-local per output jj. A in LDS with ^((row&7)<<4) swizzle
// (ds_read_b128 at 512B row stride would otherwise 16-way conflict).
__global__ __launch_bounds__(256, 2) void gru_mfma_kernel(
    const ushort* __restrict__ Abuf, const ushort* __restrict__ Bswz,
    float* __restrict__ hstate, ushort* __restrict__ Ah,
    const float* __restrict__ bih, const float* __restrict__ bhh)
{
    __shared__ ushort sA[64 * 256];   // 32 KB
    const int tid = threadIdx.x;
    const int w = tid >> 6, l = tid & 63;
    const int n0 = blockIdx.x * 64;

    #pragma unroll
    for (int i = 0; i < 8; i++) {
        int flat = tid + 256 * i;          // 0..2047
        int row = flat >> 5, ch = flat & 31;
        uint4 v = make_uint4(0u, 0u, 0u, 0u);
        int n = n0 + row;
        if (n < NN) v = *(const uint4*)&Abuf[(size_t)n * 256 + ch * 8];
        int byteoff = row * 512 + ((ch * 16) ^ ((row & 7) << 4));
        *(uint4*)((char*)sA + byteoff) = v;
    }
    __syncthreads();

    f32x4 acc[4][4][2];
    #pragma unroll
    for (int i = 0; i < 4; i++)
        #pragma unroll
        for (int g = 0; g < 4; g++)
            #pragma unroll
            for (int s = 0; s < 2; s++)
                acc[i][g][s] = (f32x4){0.f, 0.f, 0.f, 0.f};

    const bf16x8* Bf = (const bf16x8*)Bswz;
    #pragma unroll
    for (int kb = 0; kb < 8; kb++) {
        bf16x8 a[4];
        #pragma unroll
        for (int i = 0; i < 4; i++) {
            int rl = i * 16 + (l & 15);
            int byteoff = rl * 512 + (((kb * 64) + ((l >> 4) * 16)) ^ ((rl & 7) << 4));
            a[i] = *(const bf16x8*)((const char*)sA + byteoff);
        }
        bf16x8 b[4][2];
        #pragma unroll
        for (int g = 0; g < 4; g++)
            #pragma unroll
            for (int s = 0; s < 2; s++)
                b[g][s] = Bf[(size_t)(kb * 32 + g * 8 + 2 * w + s) * 64 + l];
        #pragma unroll
        for (int i = 0; i < 4; i++)
            #pragma unroll
            for (int g = 0; g < 4; g++)
                #pragma unroll
                for (int s = 0; s < 2; s++)
                    acc[i][g][s] = __builtin_amdgcn_mfma_f32_16x16x32_bf16(
                        a[i], b[g][s], acc[i][g][s], 0, 0, 0);
    }

    #pragma unroll
    for (int s = 0; s < 2; s++) {
        int jj = (2 * w + s) * 16 + (l & 15);
        float br  = bih[jj] + bhh[jj];
        float bz  = bih[128 + jj] + bhh[128 + jj];
        float bin = bih[256 + jj];
        float bhn = bhh[256 + jj];
        #pragma unroll
        for (int i = 0; i < 4; i++) {
            #pragma unroll
            for (int r = 0; r < 4; r++) {
                int n = n0 + i * 16 + (l >> 4) * 4 + r;
                if (n >= NN) continue;
                float rp = acc[i][0][s][r] + br;
                float zp = acc[i][1][s][r] + bz;
                float rg = 1.f / (1.f + expf(-rp));
                float zg = 1.f / (1.f + expf(-zp));
                float nv = tanhf(acc[i][2][s][r] + bin + rg * (acc[i][3][s][r] + bhn));
                float hold = hstate[(size_t)n * DD + jj];
                float hnew = (1.f - zg) * nv + zg * hold;
                hstate[(size_t)n * DD + jj] = hnew;
                Ah[(size_t)n * 256 + 128 + jj] = f2b(hnew);
            }
        }
    }
}

// ---------------- final linear: out[n] = h[n,:] . W_lin + b ----------------
__global__ __launch_bounds__(256) void out_kernel(
    const float* __restrict__ h, const float* __restrict__ wl,
    const float* __restrict__ bl, float* __restrict__ out)
{
    int lane = threadIdx.x & 63;
    int n = blockIdx.x * 4 + (threadIdx.x >> 6);
    if (n >= NN) return;
    const float* hp = &h[(size_t)n * DD];
    float s = hp[lane] * wl[lane] + hp[64 + lane] * wl[64 + lane];
    #pragma unroll
    for (int off = 32; off; off >>= 1) s += __shfl_down(s, off);
    if (lane == 0) out[n] = s + bl[0];
}

extern "C" void kernel_launch(void* const* d_in, const int* in_sizes, int n_in,
                              void* d_out, int out_size, void* d_ws, size_t ws_size,
                              hipStream_t stream)
{
    const float* x     = (const float*)d_in[0];
    const int*   ei    = (const int*)d_in[1];
    const float* Wg    = (const float*)d_in[2];
    const float* a_src = (const float*)d_in[3];
    const float* a_dst = (const float*)d_in[4];
    const float* b_gat = (const float*)d_in[5];
    const float* Wih   = (const float*)d_in[6];
    const float* Whh   = (const float*)d_in[7];
    const float* bih   = (const float*)d_in[8];
    const float* bhh   = (const float*)d_in[9];
    const float* Wl    = (const float*)d_in[10];
    const float* bl    = (const float*)d_in[11];
    float* out = (float*)d_out;

    float* ws = (float*)d_ws;
    float* hbuf   = ws;                         // N*128 f32
    float* gbuf   = hbuf   + (size_t)NN * DD;   // N*128 f32
    float* hstate = gbuf   + (size_t)NN * DD;   // N*128 f32
    float* alsrc  = hstate + (size_t)NN * DD;   // N*4
    float* aldst  = alsrc  + (size_t)NN * HH;   // N*4
    float* denom  = aldst  + (size_t)NN * HH;   // N*4
    ushort* Abuf  = (ushort*)(denom + (size_t)NN * HH);   // N*256 bf16 [g|h]
    ushort* Bswz  = Abuf + (size_t)NN * 256;              // 256*512 bf16

    hipMemsetAsync(hstate, 0, (size_t)NN * DD * sizeof(float), stream);
    hipMemsetAsync(Abuf, 0, (size_t)NN * 256 * sizeof(ushort), stream);
    prep_b_kernel<<<512, 256, 0, stream>>>(Wih, Whh, Bswz);

    for (int t = 0; t < TT; t++) {
        const int* srcp = ei + (size_t)t * 2 * EE;
        const int* dstp = srcp + EE;

        gat_gemm_kernel<<<(NN + 63) / 64, 256, 0, stream>>>(x, Wg, hbuf, t);
        al_kernel<<<(NN * HH + 255) / 256, 256, 0, stream>>>(hbuf, a_src, a_dst, alsrc, aldst);
        hipMemsetAsync(denom, 0, (size_t)NN * HH * sizeof(float), stream);
        hipMemsetAsync(gbuf, 0, (size_t)NN * DD * sizeof(float), stream);
        edge_denom_kernel<<<(ETOT + 255) / 256, 256, 0, stream>>>(srcp, dstp, alsrc, aldst, denom);
        edge_msg_kernel<<<(ETOT + 1) / 2, 256, 0, stream>>>(srcp, dstp, alsrc, aldst, denom, hbuf, gbuf);
        relu_bias_bf16_kernel<<<(NN * 16 + 255) / 256, 256, 0, stream>>>(gbuf, b_gat, Abuf);
        gru_mfma_kernel<<<(NN + 63) / 64, 256, 0, stream>>>(Abuf, Bswz, hstate, Abuf, bih, bhh);
    }
    out_kernel<<<(NN + 3) / 4, 256, 0, stream>>>(hstate, Wl, bl, out);
}

// Round 3
// 3954.893 us; speedup vs baseline: 3.3279x; 1.9938x over previous
//
#include <hip/hip_runtime.h>
#include <cstddef>

#define NN 50000
#define TT 12
#define FIN 128
#define DD 128
#define HH 4
#define EE 800000
#define ETOT (EE + NN)
#define NEG 0.2f

typedef __attribute__((ext_vector_type(8))) short bf16x8;
typedef __attribute__((ext_vector_type(4))) float f32x4;

__device__ __forceinline__ ushort f2b(float x) {
    unsigned int u = __builtin_bit_cast(unsigned int, x);
    unsigned int r = (u + 0x7FFFu + ((u >> 16) & 1u)) >> 16;
    return (ushort)r;
}
__device__ __forceinline__ float b2f(ushort u) {
    unsigned int v = ((unsigned int)u) << 16;
    return __builtin_bit_cast(float, v);
}

// ---------------- prep: W_gat in MFMA fragment order, hi/lo bf16 split ----------------
__global__ __launch_bounds__(256) void prep_wg_kernel(
    const float* __restrict__ Wg, ushort* __restrict__ Wgh, ushort* __restrict__ Wgl)
{
    int idx = blockIdx.x * 256 + threadIdx.x;      // < 16384
    int fi = idx >> 9, rem = idx & 511;
    int l = rem >> 3, j = rem & 7;
    int kb = fi >> 3, cf = fi & 7;
    int k = kb * 32 + (l >> 4) * 8 + j;
    int col = cf * 16 + (l & 15);
    float v = Wg[(size_t)k * DD + col];
    ushort hi = f2b(v);
    Wgh[idx] = hi;
    Wgl[idx] = f2b(v - b2f(hi));
}

// ---------------- GAT input GEMM via MFMA (hi/lo split for ~fp32 accuracy) ----------------
__global__ __launch_bounds__(256, 2) void gat_gemm_mfma_kernel(
    const float* __restrict__ x, const ushort* __restrict__ Wgh, const ushort* __restrict__ Wgl,
    float* __restrict__ hout, int t)
{
    __shared__ ushort sAh[64 * 128];   // 16 KB
    __shared__ ushort sAl[64 * 128];   // 16 KB
    const int tid = threadIdx.x;
    const int w = tid >> 6, l = tid & 63;
    const int n0 = blockIdx.x * 64;

    #pragma unroll
    for (int i = 0; i < 8; i++) {
        int fl = tid + 256 * i;            // 0..2047 = 64 rows x 32 float4
        int row = fl >> 5, q = fl & 31;
        int n = n0 + row;
        float4 v = make_float4(0.f, 0.f, 0.f, 0.f);
        if (n < NN) v = *(const float4*)&x[((size_t)n * TT + t) * FIN + q * 4];
        float vv[4] = {v.x, v.y, v.z, v.w};
        ushort hi[4], lo[4];
        #pragma unroll
        for (int j = 0; j < 4; j++) {
            hi[j] = f2b(vv[j]);
            lo[j] = f2b(vv[j] - b2f(hi[j]));
        }
        int byteoff = row * 256 + ((q * 8) ^ ((row & 7) << 4));
        *(uint2*)((char*)sAh + byteoff) = *(uint2*)hi;
        *(uint2*)((char*)sAl + byteoff) = *(uint2*)lo;
    }
    __syncthreads();

    f32x4 acc[4][2];
    #pragma unroll
    for (int i = 0; i < 4; i++)
        #pragma unroll
        for (int s = 0; s < 2; s++) acc[i][s] = (f32x4){0.f, 0.f, 0.f, 0.f};

    const bf16x8* Bh = (const bf16x8*)Wgh;
    const bf16x8* Bl = (const bf16x8*)Wgl;
    #pragma unroll
    for (int kb = 0; kb < 4; kb++) {
        bf16x8 ah[4], alo[4];
        #pragma unroll
        for (int i = 0; i < 4; i++) {
            int rl = i * 16 + (l & 15);
            int byteoff = rl * 256 + (((kb * 64) + ((l >> 4) * 16)) ^ ((rl & 7) << 4));
            ah[i]  = *(const bf16x8*)((const char*)sAh + byteoff);
            alo[i] = *(const bf16x8*)((const char*)sAl + byteoff);
        }
        bf16x8 bh[2], bl[2];
        #pragma unroll
        for (int s = 0; s < 2; s++) {
            int fi = kb * 8 + 2 * w + s;
            bh[s] = Bh[(size_t)fi * 64 + l];
            bl[s] = Bl[(size_t)fi * 64 + l];
        }
        #pragma unroll
        for (int i = 0; i < 4; i++)
            #pragma unroll
            for (int s = 0; s < 2; s++) {
                acc[i][s] = __builtin_amdgcn_mfma_f32_16x16x32_bf16(ah[i],  bh[s], acc[i][s], 0, 0, 0);
                acc[i][s] = __builtin_amdgcn_mfma_f32_16x16x32_bf16(ah[i],  bl[s], acc[i][s], 0, 0, 0);
                acc[i][s] = __builtin_amdgcn_mfma_f32_16x16x32_bf16(alo[i], bh[s], acc[i][s], 0, 0, 0);
            }
    }

    #pragma unroll
    for (int i = 0; i < 4; i++)
        #pragma unroll
        for (int s = 0; s < 2; s++) {
            int jj = (2 * w + s) * 16 + (l & 15);
            #pragma unroll
            for (int r = 0; r < 4; r++) {
                int n = n0 + i * 16 + (l >> 4) * 4 + r;
                if (n < NN) hout[(size_t)n * DD + jj] = acc[i][s][r];
            }
        }
}

// ---------------- per-node attention logits ----------------
__global__ __launch_bounds__(256) void al_kernel(
    const float* __restrict__ h, const float* __restrict__ a_src,
    const float* __restrict__ a_dst, float* __restrict__ alsrc, float* __restrict__ aldst)
{
    int gid = blockIdx.x * 256 + threadIdx.x;
    if (gid >= NN * HH) return;
    int n = gid >> 2, hd = gid & 3;
    const float* hp = &h[(size_t)n * DD + hd * 32];
    const float* ap = &a_src[hd * 32];
    const float* bp = &a_dst[hd * 32];
    float s1 = 0.f, s2 = 0.f;
    #pragma unroll
    for (int i = 0; i < 32; i += 4) {
        float4 hv = *(const float4*)&hp[i];
        float4 av = *(const float4*)&ap[i];
        float4 dv = *(const float4*)&bp[i];
        s1 += hv.x * av.x + hv.y * av.y + hv.z * av.z + hv.w * av.w;
        s2 += hv.x * dv.x + hv.y * dv.y + hv.z * dv.z + hv.w * dv.w;
    }
    alsrc[gid] = s1;
    aldst[gid] = s2;
}

// ---------------- CSR build ----------------
__global__ __launch_bounds__(256) void count_kernel(
    const int* __restrict__ dst, int* __restrict__ deg)
{
    int gid = blockIdx.x * 256 + threadIdx.x;
    if (gid >= ETOT) return;
    int d = (gid < EE) ? dst[gid] : (gid - EE);
    atomicAdd(&deg[d], 1);
}

__global__ __launch_bounds__(1024) void scan_kernel(
    const int* __restrict__ deg, int* __restrict__ rowptr, int* __restrict__ cursor)
{
    __shared__ int sums[1024];
    const int t = threadIdx.x;
    const int per = 49;                      // 1024*49 >= 50000
    int local[49];
    int base = t * per;
    int s = 0;
    #pragma unroll
    for (int i = 0; i < per; i++) {
        int idx = base + i;
        int v = (idx < NN) ? deg[idx] : 0;
        local[i] = s;
        s += v;
    }
    sums[t] = s;
    __syncthreads();
    for (int off = 1; off < 1024; off <<= 1) {
        int v = (t >= off) ? sums[t - off] : 0;
        __syncthreads();
        sums[t] += v;
        __syncthreads();
    }
    int toff = (t == 0) ? 0 : sums[t - 1];
    #pragma unroll
    for (int i = 0; i < per; i++) {
        int idx = base + i;
        if (idx < NN) {
            int r = toff + local[i];
            rowptr[idx] = r;
            cursor[idx] = r;
        }
    }
}

__global__ __launch_bounds__(256) void fill_kernel(
    const int* __restrict__ src, const int* __restrict__ dst,
    int* __restrict__ cursor, int* __restrict__ csr_src)
{
    int gid = blockIdx.x * 256 + threadIdx.x;
    if (gid >= ETOT) return;
    int s, d;
    if (gid < EE) { s = src[gid]; d = dst[gid]; }
    else { s = gid - EE; d = s; }
    int pos = atomicAdd(&cursor[d], 1);
    csr_src[pos] = s;
}

// ---------------- fused GAT aggregate: softmax + gather + bias + relu -> bf16 ----------------
// One block per dst node; 128 threads = 128 channels.
__global__ __launch_bounds__(128) void gather_kernel(
    const int* __restrict__ rowptr, const int* __restrict__ deg, const int* __restrict__ csr_src,
    const float* __restrict__ alsrc, const float* __restrict__ aldst,
    const float* __restrict__ hsrc, const float* __restrict__ bgat,
    ushort* __restrict__ Abuf)
{
    __shared__ int   ssrc[128];
    __shared__ float salpha[128][5];
    __shared__ float sden[8];
    const int d = blockIdx.x;
    const int t = threadIdx.x;
    const int start = rowptr[d];
    const int cnt = deg[d];
    float4 ad = *(const float4*)&aldst[(size_t)d * 4];

    // phase 1: softmax denominator over all incoming edges
    float h0 = 0.f, h1 = 0.f, h2 = 0.f, h3 = 0.f;
    for (int base = 0; base < cnt; base += 128) {
        int e = base + t;
        if (e < cnt) {
            int s = csr_src[start + e];
            float4 as = *(const float4*)&alsrc[(size_t)s * 4];
            float e0 = as.x + ad.x, e1 = as.y + ad.y, e2 = as.z + ad.z, e3 = as.w + ad.w;
            e0 = e0 > 0.f ? e0 : NEG * e0;
            e1 = e1 > 0.f ? e1 : NEG * e1;
            e2 = e2 > 0.f ? e2 : NEG * e2;
            e3 = e3 > 0.f ? e3 : NEG * e3;
            h0 += __expf(e0); h1 += __expf(e1); h2 += __expf(e2); h3 += __expf(e3);
        }
    }
    #pragma unroll
    for (int off = 32; off; off >>= 1) {
        h0 += __shfl_down(h0, off);
        h1 += __shfl_down(h1, off);
        h2 += __shfl_down(h2, off);
        h3 += __shfl_down(h3, off);
    }
    if ((t & 63) == 0) {
        int wv = t >> 6;
        sden[wv * 4 + 0] = h0; sden[wv * 4 + 1] = h1;
        sden[wv * 4 + 2] = h2; sden[wv * 4 + 3] = h3;
    }
    __syncthreads();
    float inv0 = 1.f / (sden[0] + sden[4] + 1e-16f);
    float inv1 = 1.f / (sden[1] + sden[5] + 1e-16f);
    float inv2 = 1.f / (sden[2] + sden[6] + 1e-16f);
    float inv3 = 1.f / (sden[3] + sden[7] + 1e-16f);

    // phase 2: weighted gather
    const int hd = t >> 5;
    float acc = 0.f;
    for (int base = 0; base < cnt; base += 128) {
        int e = base + t;
        __syncthreads();
        if (e < cnt) {
            int s = csr_src[start + e];
            ssrc[t] = s;
            float4 as = *(const float4*)&alsrc[(size_t)s * 4];
            float e0 = as.x + ad.x, e1 = as.y + ad.y, e2 = as.z + ad.z, e3 = as.w + ad.w;
            e0 = e0 > 0.f ? e0 : NEG * e0;
            e1 = e1 > 0.f ? e1 : NEG * e1;
            e2 = e2 > 0.f ? e2 : NEG * e2;
            e3 = e3 > 0.f ? e3 : NEG * e3;
            salpha[t][0] = __expf(e0) * inv0;
            salpha[t][1] = __expf(e1) * inv1;
            salpha[t][2] = __expf(e2) * inv2;
            salpha[t][3] = __expf(e3) * inv3;
        }
        __syncthreads();
        int m = min(128, cnt - base);
        #pragma unroll 2
        for (int j = 0; j < m; j++) {
            int s = ssrc[j];
            float a = salpha[j][hd];
            acc += hsrc[(size_t)s * DD + t] * a;
        }
    }
    float g = fmaxf(acc + bgat[t], 0.f);
    Abuf[(size_t)d * 256 + t] = f2b(g);
}

// ---------------- prep: bf16 gate matrix in MFMA fragment order ----------------
__global__ __launch_bounds__(256) void prep_b_kernel(
    const float* __restrict__ Wih, const float* __restrict__ Whh, ushort* __restrict__ Bswz)
{
    int idx = blockIdx.x * 256 + threadIdx.x;      // < 131072
    int fi = idx >> 9;
    int rem = idx & 511;
    int l = rem >> 3, j = rem & 7;
    int kb = fi >> 5, c = fi & 31;
    int g = c >> 3, cf = c & 7;
    int k = kb * 32 + (l >> 4) * 8 + j;
    int jj = cf * 16 + (l & 15);
    float v;
    if (g == 0)      v = (k < 128) ? Wih[(size_t)jj * DD + k]         : Whh[(size_t)jj * DD + k - 128];
    else if (g == 1) v = (k < 128) ? Wih[(size_t)(128 + jj) * DD + k] : Whh[(size_t)(128 + jj) * DD + k - 128];
    else if (g == 2) v = (k < 128) ? Wih[(size_t)(256 + jj) * DD + k] : 0.f;
    else             v = (k < 128) ? 0.f : Whh[(size_t)(256 + jj) * DD + k - 128];
    Bswz[idx] = f2b(v);
}

// ---------------- fused GRU step via bf16 MFMA ----------------
__global__ __launch_bounds__(256, 2) void gru_mfma_kernel(
    const ushort* __restrict__ Abuf, const ushort* __restrict__ Bswz,
    float* __restrict__ hstate, ushort* __restrict__ Ah,
    const float* __restrict__ bih, const float* __restrict__ bhh)
{
    __shared__ ushort sA[64 * 256];   // 32 KB
    const int tid = threadIdx.x;
    const int w = tid >> 6, l = tid & 63;
    const int n0 = blockIdx.x * 64;

    #pragma unroll
    for (int i = 0; i < 8; i++) {
        int flat = tid + 256 * i;          // 0..2047
        int row = flat >> 5, ch = flat & 31;
        uint4 v = make_uint4(0u, 0u, 0u, 0u);
        int n = n0 + row;
        if (n < NN) v = *(const uint4*)&Abuf[(size_t)n * 256 + ch * 8];
        int byteoff = row * 512 + ((ch * 16) ^ ((row & 7) << 4));
        *(uint4*)((char*)sA + byteoff) = v;
    }
    __syncthreads();

    f32x4 acc[4][4][2];
    #pragma unroll
    for (int i = 0; i < 4; i++)
        #pragma unroll
        for (int g = 0; g < 4; g++)
            #pragma unroll
            for (int s = 0; s < 2; s++)
                acc[i][g][s] = (f32x4){0.f, 0.f, 0.f, 0.f};

    const bf16x8* Bf = (const bf16x8*)Bswz;
    #pragma unroll
    for (int kb = 0; kb < 8; kb++) {
        bf16x8 a[4];
        #pragma unroll
        for (int i = 0; i < 4; i++) {
            int rl = i * 16 + (l & 15);
            int byteoff = rl * 512 + (((kb * 64) + ((l >> 4) * 16)) ^ ((rl & 7) << 4));
            a[i] = *(const bf16x8*)((const char*)sA + byteoff);
        }
        bf16x8 b[4][2];
        #pragma unroll
        for (int g = 0; g < 4; g++)
            #pragma unroll
            for (int s = 0; s < 2; s++)
                b[g][s] = Bf[(size_t)(kb * 32 + g * 8 + 2 * w + s) * 64 + l];
        #pragma unroll
        for (int i = 0; i < 4; i++)
            #pragma unroll
            for (int g = 0; g < 4; g++)
                #pragma unroll
                for (int s = 0; s < 2; s++)
                    acc[i][g][s] = __builtin_amdgcn_mfma_f32_16x16x32_bf16(
                        a[i], b[g][s], acc[i][g][s], 0, 0, 0);
    }

    #pragma unroll
    for (int s = 0; s < 2; s++) {
        int jj = (2 * w + s) * 16 + (l & 15);
        float br  = bih[jj] + bhh[jj];
        float bz  = bih[128 + jj] + bhh[128 + jj];
        float bin = bih[256 + jj];
        float bhn = bhh[256 + jj];
        #pragma unroll
        for (int i = 0; i < 4; i++) {
            #pragma unroll
            for (int r = 0; r < 4; r++) {
                int n = n0 + i * 16 + (l >> 4) * 4 + r;
                if (n >= NN) continue;
                float rp = acc[i][0][s][r] + br;
                float zp = acc[i][1][s][r] + bz;
                float rg = 1.f / (1.f + expf(-rp));
                float zg = 1.f / (1.f + expf(-zp));
                float nv = tanhf(acc[i][2][s][r] + bin + rg * (acc[i][3][s][r] + bhn));
                float hold = hstate[(size_t)n * DD + jj];
                float hnew = (1.f - zg) * nv + zg * hold;
                hstate[(size_t)n * DD + jj] = hnew;
                Ah[(size_t)n * 256 + 128 + jj] = f2b(hnew);
            }
        }
    }
}

// ---------------- final linear ----------------
__global__ __launch_bounds__(256) void out_kernel(
    const float* __restrict__ h, const float* __restrict__ wl,
    const float* __restrict__ bl, float* __restrict__ out)
{
    int lane = threadIdx.x & 63;
    int n = blockIdx.x * 4 + (threadIdx.x >> 6);
    if (n >= NN) return;
    const float* hp = &h[(size_t)n * DD];
    float s = hp[lane] * wl[lane] + hp[64 + lane] * wl[64 + lane];
    #pragma unroll
    for (int off = 32; off; off >>= 1) s += __shfl_down(s, off);
    if (lane == 0) out[n] = s + bl[0];
}

extern "C" void kernel_launch(void* const* d_in, const int* in_sizes, int n_in,
                              void* d_out, int out_size, void* d_ws, size_t ws_size,
                              hipStream_t stream)
{
    const float* x     = (const float*)d_in[0];
    const int*   ei    = (const int*)d_in[1];
    const float* Wg    = (const float*)d_in[2];
    const float* a_src = (const float*)d_in[3];
    const float* a_dst = (const float*)d_in[4];
    const float* b_gat = (const float*)d_in[5];
    const float* Wih   = (const float*)d_in[6];
    const float* Whh   = (const float*)d_in[7];
    const float* bih   = (const float*)d_in[8];
    const float* bhh   = (const float*)d_in[9];
    const float* Wl    = (const float*)d_in[10];
    const float* bl    = (const float*)d_in[11];
    float* out = (float*)d_out;

    float* ws = (float*)d_ws;
    float* hbuf   = ws;                          // N*128 f32
    float* hstate = hbuf   + (size_t)NN * DD;    // N*128 f32
    float* alsrc  = hstate + (size_t)NN * DD;    // N*4
    float* aldst  = alsrc  + (size_t)NN * HH;    // N*4
    ushort* Abuf  = (ushort*)(aldst + (size_t)NN * HH);   // N*256 bf16 [g|h]
    ushort* Bswz  = Abuf + (size_t)NN * 256;              // 131072
    ushort* Wgh   = Bswz + 131072;                        // 16384
    ushort* Wgl   = Wgh + 16384;                          // 16384
    int* deg      = (int*)(Wgl + 16384);                  // N
    int* rowptr   = deg + NN;                             // N
    int* cursor   = rowptr + NN;                          // N
    int* csr_src  = cursor + NN;                          // ETOT

    hipMemsetAsync(hstate, 0, (size_t)NN * DD * sizeof(float), stream);
    hipMemsetAsync(Abuf, 0, (size_t)NN * 256 * sizeof(ushort), stream);
    prep_b_kernel<<<512, 256, 0, stream>>>(Wih, Whh, Bswz);
    prep_wg_kernel<<<64, 256, 0, stream>>>(Wg, Wgh, Wgl);

    for (int t = 0; t < TT; t++) {
        const int* srcp = ei + (size_t)t * 2 * EE;
        const int* dstp = srcp + EE;

        gat_gemm_mfma_kernel<<<(NN + 63) / 64, 256, 0, stream>>>(x, Wgh, Wgl, hbuf, t);
        al_kernel<<<(NN * HH + 255) / 256, 256, 0, stream>>>(hbuf, a_src, a_dst, alsrc, aldst);

        hipMemsetAsync(deg, 0, (size_t)NN * sizeof(int), stream);
        count_kernel<<<(ETOT + 255) / 256, 256, 0, stream>>>(dstp, deg);
        scan_kernel<<<1, 1024, 0, stream>>>(deg, rowptr, cursor);
        fill_kernel<<<(ETOT + 255) / 256, 256, 0, stream>>>(srcp, dstp, cursor, csr_src);

        gather_kernel<<<NN, 128, 0, stream>>>(rowptr, deg, csr_src, alsrc, aldst, hbuf, b_gat, Abuf);
        gru_mfma_kernel<<<(NN + 63) / 64, 256, 0, stream>>>(Abuf, Bswz, hstate, Abuf, bih, bhh);
    }
    out_kernel<<<(NN + 3) / 4, 256, 0, stream>>>(hstate, Wl, bl, out);
}

// Round 4
// 2852.818 us; speedup vs baseline: 4.6134x; 1.3863x over previous
//
#include <hip/hip_runtime.h>
#include <cstddef>

#define NN 50000
#define TT 12
#define FIN 128
#define DD 128
#define HH 4
#define EE 800000
#define ETOT (EE + NN)
#define MTOT (NN * TT)          // 600000 rows, divisible by 64
#define NEG 0.2f

typedef __attribute__((ext_vector_type(8))) short bf16x8;
typedef __attribute__((ext_vector_type(4))) float f32x4;

__device__ __forceinline__ ushort f2b(float x) {
    unsigned int u = __builtin_bit_cast(unsigned int, x);
    unsigned int r = (u + 0x7FFFu + ((u >> 16) & 1u)) >> 16;
    return (ushort)r;
}
__device__ __forceinline__ float b2f(ushort u) {
    unsigned int v = ((unsigned int)u) << 16;
    return __builtin_bit_cast(float, v);
}

// ---------------- prep: W_gat in MFMA fragment order, hi/lo bf16 split ----------------
__global__ __launch_bounds__(256) void prep_wg_kernel(
    const float* __restrict__ Wg, ushort* __restrict__ Wgh, ushort* __restrict__ Wgl)
{
    int idx = blockIdx.x * 256 + threadIdx.x;      // < 16384
    int fi = idx >> 9, rem = idx & 511;
    int l = rem >> 3, j = rem & 7;
    int kb = fi >> 3, cf = fi & 7;
    int k = kb * 32 + (l >> 4) * 8 + j;
    int col = cf * 16 + (l & 15);
    float v = Wg[(size_t)k * DD + col];
    ushort hi = f2b(v);
    Wgh[idx] = hi;
    Wgl[idx] = f2b(v - b2f(hi));
}

// ---------------- all-t GAT GEMM: hbf[t][n][128] (bf16) = x @ Wg ----------------
// M = 600000 rows (m = n*12 + t), K = 128. W hi/lo split (2 MFMA passes).
__global__ __launch_bounds__(256) void gemm_all_kernel(
    const float* __restrict__ x, const ushort* __restrict__ Wgh, const ushort* __restrict__ Wgl,
    ushort* __restrict__ hbf)
{
    __shared__ ushort sAh[64 * 128];   // 16 KB
    const int tid = threadIdx.x;
    const int w = tid >> 6, l = tid & 63;
    const int m0 = blockIdx.x * 64;

    #pragma unroll
    for (int i = 0; i < 8; i++) {
        int fl = tid + 256 * i;            // 0..2047 = 64 rows x 32 float4
        int row = fl >> 5, q = fl & 31;
        float4 v = *(const float4*)&x[(size_t)(m0 + row) * FIN + q * 4];
        ushort hi[4] = {f2b(v.x), f2b(v.y), f2b(v.z), f2b(v.w)};
        int byteoff = row * 256 + ((q * 8) ^ ((row & 7) << 4));
        *(uint2*)((char*)sAh + byteoff) = *(uint2*)hi;
    }
    __syncthreads();

    f32x4 acc[4][2];
    #pragma unroll
    for (int i = 0; i < 4; i++)
        #pragma unroll
        for (int s = 0; s < 2; s++) acc[i][s] = (f32x4){0.f, 0.f, 0.f, 0.f};

    const bf16x8* Bh = (const bf16x8*)Wgh;
    const bf16x8* Bl = (const bf16x8*)Wgl;
    #pragma unroll
    for (int kb = 0; kb < 4; kb++) {
        bf16x8 ah[4];
        #pragma unroll
        for (int i = 0; i < 4; i++) {
            int rl = i * 16 + (l & 15);
            int byteoff = rl * 256 + (((kb * 64) + ((l >> 4) * 16)) ^ ((rl & 7) << 4));
            ah[i] = *(const bf16x8*)((const char*)sAh + byteoff);
        }
        bf16x8 bh[2], bl[2];
        #pragma unroll
        for (int s = 0; s < 2; s++) {
            int fi = kb * 8 + 2 * w + s;
            bh[s] = Bh[(size_t)fi * 64 + l];
            bl[s] = Bl[(size_t)fi * 64 + l];
        }
        #pragma unroll
        for (int i = 0; i < 4; i++)
            #pragma unroll
            for (int s = 0; s < 2; s++) {
                acc[i][s] = __builtin_amdgcn_mfma_f32_16x16x32_bf16(ah[i], bh[s], acc[i][s], 0, 0, 0);
                acc[i][s] = __builtin_amdgcn_mfma_f32_16x16x32_bf16(ah[i], bl[s], acc[i][s], 0, 0, 0);
            }
    }

    #pragma unroll
    for (int i = 0; i < 4; i++)
        #pragma unroll
        for (int s = 0; s < 2; s++) {
            int jj = (2 * w + s) * 16 + (l & 15);
            #pragma unroll
            for (int r = 0; r < 4; r++) {
                int m = m0 + i * 16 + (l >> 4) * 4 + r;
                int n = m / TT;
                int t = m - n * TT;
                hbf[((size_t)t * NN + n) * DD + jj] = f2b(acc[i][s][r]);
            }
        }
}

// ---------------- all-t attention logits from bf16 h ----------------
__global__ __launch_bounds__(256) void al_all_kernel(
    const ushort* __restrict__ hbf, const float* __restrict__ a_src,
    const float* __restrict__ a_dst, float* __restrict__ alsrc, float* __restrict__ aldst)
{
    int gid = blockIdx.x * 256 + threadIdx.x;
    if (gid >= TT * NN * HH) return;
    int row = gid >> 2, hd = gid & 3;      // row = t*NN + n
    const uint* hp = (const uint*)&hbf[(size_t)row * DD + hd * 32];
    const float* ap = &a_src[hd * 32];
    const float* bp = &a_dst[hd * 32];
    float s1 = 0.f, s2 = 0.f;
    #pragma unroll
    for (int i = 0; i < 16; i++) {
        uint hw = hp[i];
        float h0 = b2f((ushort)(hw & 0xffffu));
        float h1 = b2f((ushort)(hw >> 16));
        s1 += h0 * ap[2 * i] + h1 * ap[2 * i + 1];
        s2 += h0 * bp[2 * i] + h1 * bp[2 * i + 1];
    }
    alsrc[gid] = s1;
    aldst[gid] = s2;
}

// ---------------- batched CSR build (all 12 timesteps) ----------------
__global__ __launch_bounds__(256) void count12_kernel(
    const int* __restrict__ ei, int* __restrict__ deg)
{
    int gid = blockIdx.x * 256 + threadIdx.x;
    if (gid >= TT * ETOT) return;
    int t = gid / ETOT;
    int e = gid - t * ETOT;
    const int* dst = ei + (size_t)t * 2 * EE + EE;
    int d = (e < EE) ? dst[e] : (e - EE);
    atomicAdd(&deg[t * NN + d], 1);
}

__global__ __launch_bounds__(1024) void scan12_kernel(
    const int* __restrict__ deg, int* __restrict__ rowptr, int* __restrict__ cursor)
{
    __shared__ int sums[1024];
    const int t = blockIdx.x;
    const int th = threadIdx.x;
    const int per = 49;                      // 1024*49 >= 50000
    const int* dp = deg + (size_t)t * NN;
    int* rp = rowptr + (size_t)t * NN;
    int* cp = cursor + (size_t)t * NN;
    int local[49];
    int base = th * per;
    int s = 0;
    #pragma unroll
    for (int i = 0; i < per; i++) {
        int idx = base + i;
        int v = (idx < NN) ? dp[idx] : 0;
        local[i] = s;
        s += v;
    }
    sums[th] = s;
    __syncthreads();
    for (int off = 1; off < 1024; off <<= 1) {
        int v = (th >= off) ? sums[th - off] : 0;
        __syncthreads();
        sums[th] += v;
        __syncthreads();
    }
    int toff = (th == 0) ? 0 : sums[th - 1];
    #pragma unroll
    for (int i = 0; i < per; i++) {
        int idx = base + i;
        if (idx < NN) {
            int r = toff + local[i];
            rp[idx] = r;
            cp[idx] = r;
        }
    }
}

__global__ __launch_bounds__(256) void fill12_kernel(
    const int* __restrict__ ei, int* __restrict__ cursor, int* __restrict__ csr_src)
{
    int gid = blockIdx.x * 256 + threadIdx.x;
    if (gid >= TT * ETOT) return;
    int t = gid / ETOT;
    int e = gid - t * ETOT;
    const int* src = ei + (size_t)t * 2 * EE;
    const int* dst = src + EE;
    int s, d;
    if (e < EE) { s = src[e]; d = dst[e]; }
    else { s = e - EE; d = s; }
    int pos = atomicAdd(&cursor[t * NN + d], 1);
    csr_src[(size_t)t * ETOT + pos] = s;
}

// ---------------- fused GAT aggregate: 1 wave/node, 2 channels/lane ----------------
__global__ __launch_bounds__(256) void gather_kernel(
    const int* __restrict__ rowptr, const int* __restrict__ deg, const int* __restrict__ csr_src,
    const float* __restrict__ alsrc, const float* __restrict__ aldst,
    const uint* __restrict__ hbf32, const float* __restrict__ bgat,
    uint* __restrict__ Ag)
{
    const int wv = threadIdx.x >> 6;
    const int lane = threadIdx.x & 63;
    const int d = blockIdx.x * 4 + wv;
    if (d >= NN) return;
    const int start = rowptr[d];
    const int cnt = deg[d];
    const int hd = lane >> 4;
    float4 ad4 = *(const float4*)&aldst[(size_t)d * 4];

    // phase 1: softmax denominators (strided + butterfly)
    float s0 = 0.f, s1 = 0.f, s2 = 0.f, s3 = 0.f;
    for (int e = lane; e < cnt; e += 64) {
        int s = csr_src[start + e];
        float4 as = *(const float4*)&alsrc[(size_t)s * 4];
        float e0 = as.x + ad4.x, e1 = as.y + ad4.y, e2 = as.z + ad4.z, e3 = as.w + ad4.w;
        e0 = fmaxf(e0, NEG * e0); e1 = fmaxf(e1, NEG * e1);
        e2 = fmaxf(e2, NEG * e2); e3 = fmaxf(e3, NEG * e3);
        s0 += __expf(e0); s1 += __expf(e1); s2 += __expf(e2); s3 += __expf(e3);
    }
    #pragma unroll
    for (int off = 1; off < 64; off <<= 1) {
        s0 += __shfl_xor(s0, off);
        s1 += __shfl_xor(s1, off);
        s2 += __shfl_xor(s2, off);
        s3 += __shfl_xor(s3, off);
    }
    float inv0 = 1.f / (s0 + 1e-16f), inv1 = 1.f / (s1 + 1e-16f);
    float inv2 = 1.f / (s2 + 1e-16f), inv3 = 1.f / (s3 + 1e-16f);
    float invh = (hd == 0) ? inv0 : (hd == 1) ? inv1 : (hd == 2) ? inv2 : inv3;
    float adh  = (hd == 0) ? ad4.x : (hd == 1) ? ad4.y : (hd == 2) ? ad4.z : ad4.w;

    // phase 2: all lanes walk every edge; lane owns channels 2*lane, 2*lane+1
    float acc0 = 0.f, acc1 = 0.f;
    #pragma unroll 2
    for (int e = 0; e < cnt; e++) {
        int s = csr_src[start + e];
        float a = alsrc[(size_t)s * 4 + hd] + adh;
        a = fmaxf(a, NEG * a);
        float p = __expf(a) * invh;
        uint hw = hbf32[(size_t)s * 64 + lane];
        acc0 += __builtin_bit_cast(float, hw << 16) * p;
        acc1 += __builtin_bit_cast(float, hw & 0xffff0000u) * p;
    }
    float g0 = fmaxf(acc0 + bgat[2 * lane], 0.f);
    float g1 = fmaxf(acc1 + bgat[2 * lane + 1], 0.f);
    Ag[(size_t)d * 128 + lane] = (uint)f2b(g0) | ((uint)f2b(g1) << 16);
}

// ---------------- prep: bf16 gate matrix in MFMA fragment order ----------------
__global__ __launch_bounds__(256) void prep_b_kernel(
    const float* __restrict__ Wih, const float* __restrict__ Whh, ushort* __restrict__ Bswz)
{
    int idx = blockIdx.x * 256 + threadIdx.x;      // < 131072
    int fi = idx >> 9;
    int rem = idx & 511;
    int l = rem >> 3, j = rem & 7;
    int kb = fi >> 5, c = fi & 31;
    int g = c >> 3, cf = c & 7;
    int k = kb * 32 + (l >> 4) * 8 + j;
    int jj = cf * 16 + (l & 15);
    float v;
    if (g == 0)      v = (k < 128) ? Wih[(size_t)jj * DD + k]         : Whh[(size_t)jj * DD + k - 128];
    else if (g == 1) v = (k < 128) ? Wih[(size_t)(128 + jj) * DD + k] : Whh[(size_t)(128 + jj) * DD + k - 128];
    else if (g == 2) v = (k < 128) ? Wih[(size_t)(256 + jj) * DD + k] : 0.f;
    else             v = (k < 128) ? 0.f : Whh[(size_t)(256 + jj) * DD + k - 128];
    Bswz[idx] = f2b(v);
}

// ---------------- fused GRU step via bf16 MFMA ----------------
__global__ __launch_bounds__(256, 2) void gru_mfma_kernel(
    const ushort* __restrict__ Abuf, const ushort* __restrict__ Bswz,
    float* __restrict__ hstate, ushort* __restrict__ Ah,
    const float* __restrict__ bih, const float* __restrict__ bhh)
{
    __shared__ ushort sA[64 * 256];   // 32 KB
    const int tid = threadIdx.x;
    const int w = tid >> 6, l = tid & 63;
    const int n0 = blockIdx.x * 64;

    #pragma unroll
    for (int i = 0; i < 8; i++) {
        int flat = tid + 256 * i;          // 0..2047
        int row = flat >> 5, ch = flat & 31;
        uint4 v = make_uint4(0u, 0u, 0u, 0u);
        int n = n0 + row;
        if (n < NN) v = *(const uint4*)&Abuf[(size_t)n * 256 + ch * 8];
        int byteoff = row * 512 + ((ch * 16) ^ ((row & 7) << 4));
        *(uint4*)((char*)sA + byteoff) = v;
    }
    __syncthreads();

    f32x4 acc[4][4][2];
    #pragma unroll
    for (int i = 0; i < 4; i++)
        #pragma unroll
        for (int g = 0; g < 4; g++)
            #pragma unroll
            for (int s = 0; s < 2; s++)
                acc[i][g][s] = (f32x4){0.f, 0.f, 0.f, 0.f};

    const bf16x8* Bf = (const bf16x8*)Bswz;
    #pragma unroll
    for (int kb = 0; kb < 8; kb++) {
        bf16x8 a[4];
        #pragma unroll
        for (int i = 0; i < 4; i++) {
            int rl = i * 16 + (l & 15);
            int byteoff = rl * 512 + (((kb * 64) + ((l >> 4) * 16)) ^ ((rl & 7) << 4));
            a[i] = *(const bf16x8*)((const char*)sA + byteoff);
        }
        bf16x8 b[4][2];
        #pragma unroll
        for (int g = 0; g < 4; g++)
            #pragma unroll
            for (int s = 0; s < 2; s++)
                b[g][s] = Bf[(size_t)(kb * 32 + g * 8 + 2 * w + s) * 64 + l];
        #pragma unroll
        for (int i = 0; i < 4; i++)
            #pragma unroll
            for (int g = 0; g < 4; g++)
                #pragma unroll
                for (int s = 0; s < 2; s++)
                    acc[i][g][s] = __builtin_amdgcn_mfma_f32_16x16x32_bf16(
                        a[i], b[g][s], acc[i][g][s], 0, 0, 0);
    }

    #pragma unroll
    for (int s = 0; s < 2; s++) {
        int jj = (2 * w + s) * 16 + (l & 15);
        float br  = bih[jj] + bhh[jj];
        float bz  = bih[128 + jj] + bhh[128 + jj];
        float bin = bih[256 + jj];
        float bhn = bhh[256 + jj];
        #pragma unroll
        for (int i = 0; i < 4; i++) {
            #pragma unroll
            for (int r = 0; r < 4; r++) {
                int n = n0 + i * 16 + (l >> 4) * 4 + r;
                if (n >= NN) continue;
                float rp = acc[i][0][s][r] + br;
                float zp = acc[i][1][s][r] + bz;
                float rg = 1.f / (1.f + expf(-rp));
                float zg = 1.f / (1.f + expf(-zp));
                float nv = tanhf(acc[i][2][s][r] + bin + rg * (acc[i][3][s][r] + bhn));
                float hold = hstate[(size_t)n * DD + jj];
                float hnew = (1.f - zg) * nv + zg * hold;
                hstate[(size_t)n * DD + jj] = hnew;
                Ah[(size_t)n * 256 + 128 + jj] = f2b(hnew);
            }
        }
    }
}

// ---------------- final linear ----------------
__global__ __launch_bounds__(256) void out_kernel(
    const float* __restrict__ h, const float* __restrict__ wl,
    const float* __restrict__ bl, float* __restrict__ out)
{
    int lane = threadIdx.x & 63;
    int n = blockIdx.x * 4 + (threadIdx.x >> 6);
    if (n >= NN) return;
    const float* hp = &h[(size_t)n * DD];
    float s = hp[lane] * wl[lane] + hp[64 + lane] * wl[64 + lane];
    #pragma unroll
    for (int off = 32; off; off >>= 1) s += __shfl_down(s, off);
    if (lane == 0) out[n] = s + bl[0];
}

extern "C" void kernel_launch(void* const* d_in, const int* in_sizes, int n_in,
                              void* d_out, int out_size, void* d_ws, size_t ws_size,
                              hipStream_t stream)
{
    const float* x     = (const float*)d_in[0];
    const int*   ei    = (const int*)d_in[1];
    const float* Wg    = (const float*)d_in[2];
    const float* a_src = (const float*)d_in[3];
    const float* a_dst = (const float*)d_in[4];
    const float* b_gat = (const float*)d_in[5];
    const float* Wih   = (const float*)d_in[6];
    const float* Whh   = (const float*)d_in[7];
    const float* bih   = (const float*)d_in[8];
    const float* bhh   = (const float*)d_in[9];
    const float* Wl    = (const float*)d_in[10];
    const float* bl    = (const float*)d_in[11];
    float* out = (float*)d_out;

    char* ws = (char*)d_ws;
    float* hstate  = (float*)ws;                                  ws += (size_t)NN * DD * 4;        // 25.6 MB
    float* alsrc   = (float*)ws;                                  ws += (size_t)TT * NN * HH * 4;   // 9.6 MB
    float* aldst   = (float*)ws;                                  ws += (size_t)TT * NN * HH * 4;   // 9.6 MB
    ushort* Abuf   = (ushort*)ws;                                 ws += (size_t)NN * 256 * 2;       // 25.6 MB
    ushort* Bswz   = (ushort*)ws;                                 ws += 131072 * 2;
    ushort* Wgh    = (ushort*)ws;                                 ws += 16384 * 2;
    ushort* Wgl    = (ushort*)ws;                                 ws += 16384 * 2;
    ushort* hbf    = (ushort*)ws;                                 ws += (size_t)TT * NN * DD * 2;   // 153.6 MB
    int* deg       = (int*)ws;                                    ws += (size_t)TT * NN * 4;        // 2.4 MB
    int* rowptr    = (int*)ws;                                    ws += (size_t)TT * NN * 4;
    int* cursor    = (int*)ws;                                    ws += (size_t)TT * NN * 4;
    int* csr_src   = (int*)ws;                                    ws += (size_t)TT * ETOT * 4;      // 40.8 MB

    hipMemsetAsync(hstate, 0, (size_t)NN * DD * sizeof(float), stream);
    hipMemsetAsync(Abuf, 0, (size_t)NN * 256 * sizeof(ushort), stream);
    hipMemsetAsync(deg, 0, (size_t)TT * NN * sizeof(int), stream);

    prep_b_kernel<<<512, 256, 0, stream>>>(Wih, Whh, Bswz);
    prep_wg_kernel<<<64, 256, 0, stream>>>(Wg, Wgh, Wgl);

    gemm_all_kernel<<<MTOT / 64, 256, 0, stream>>>(x, Wgh, Wgl, hbf);
    al_all_kernel<<<(TT * NN * HH + 255) / 256, 256, 0, stream>>>(hbf, a_src, a_dst, alsrc, aldst);

    count12_kernel<<<(TT * ETOT + 255) / 256, 256, 0, stream>>>(ei, deg);
    scan12_kernel<<<TT, 1024, 0, stream>>>(deg, rowptr, cursor);
    fill12_kernel<<<(TT * ETOT + 255) / 256, 256, 0, stream>>>(ei, cursor, csr_src);

    for (int t = 0; t < TT; t++) {
        gather_kernel<<<(NN + 3) / 4, 256, 0, stream>>>(
            rowptr + (size_t)t * NN, deg + (size_t)t * NN, csr_src + (size_t)t * ETOT,
            alsrc + (size_t)t * NN * HH, aldst + (size_t)t * NN * HH,
            (const uint*)(hbf + (size_t)t * NN * DD), b_gat, (uint*)Abuf);
        gru_mfma_kernel<<<(NN + 63) / 64, 256, 0, stream>>>(Abuf, Bswz, hstate, Abuf, bih, bhh);
    }
    out_kernel<<<(NN + 3) / 4, 256, 0, stream>>>(hstate, Wl, bl, out);
}